// Round 4
// baseline (1042.410 us; speedup 1.0000x reference)
//
#include <hip/hip_runtime.h>
#include <math.h>

// Problem constants (fixed by setup_inputs)
#define BATCH 32
#define TS    512     // Ts (phonemes / Tx)
#define TL    2048    // Tl (lip frames / Ty)
#define DD    256     // embedding dim
#define NEGV  -1e9f

// d_out sections (floats)
#define SIM_OFF   ((size_t)0)
#define GT_OFF    ((size_t)BATCH*TS*TL)
#define ALIGN_OFF ((size_t)2*BATCH*TS*TL)
#define DPRED_OFF ((size_t)3*BATCH*TS*TL)

// ---------------- ws layout (bytes) ----------------
#define WS_MEAN   0
#define WS_COF    256
#define WS_LSCALE 512
#define WS_TSCALE 262656
#define WS_BEGIN  328192
#define WS_END    393728
#define WS_START2 459264
#define WS_END2   524800

// ============================================================
// Kernel 1: row norms -> scales.
// ============================================================
__global__ __launch_bounds__(256) void norm_kernel(const float* __restrict__ lip,
                                                   const float* __restrict__ phon,
                                                   float* __restrict__ lip_scale,
                                                   float* __restrict__ text_scale) {
    const int wave = threadIdx.x >> 6, lane = threadIdx.x & 63;
    const int row = blockIdx.x * 4 + wave;
    const int NL = BATCH * TL;
    const float* src = (row < NL) ? (lip + (size_t)row * DD)
                                  : (phon + (size_t)(row - NL) * DD);
    float4 q = *(const float4*)(src + lane * 4);
    float ss = q.x*q.x + q.y*q.y + q.z*q.z + q.w*q.w;
    #pragma unroll
    for (int off = 32; off; off >>= 1) ss += __shfl_xor(ss, off);
    if (lane == 0) {
        if (row < NL) lip_scale[row] = 1.0f / sqrtf(ss);
        else          text_scale[row - NL] = 1.0f / (sqrtf(ss) + 1.0f);
    }
}

// ============================================================
// Kernel 2: per-batch duration prep. One block (512 thr) per batch.
// ============================================================
__global__ __launch_bounds__(512) void prep_kernel(const int* __restrict__ d_targets,
                                                   const int* __restrict__ lip_lens,
                                                   int* __restrict__ begins,
                                                   int* __restrict__ ends,
                                                   float* __restrict__ cof_arr) {
    __shared__ int   si[512];
    __shared__ float sf[512];
    __shared__ int   sx[512];
    const int b = blockIdx.x, t = threadIdx.x;
    const int d = d_targets[b * TS + t];
    const int lipL = lip_lens[b];

    si[t] = d; __syncthreads();
    for (int off = 256; off; off >>= 1) { if (t < off) si[t] += si[t + off]; __syncthreads(); }
    const int sum_d = si[0]; __syncthreads();

    const float cofv = (float)sum_d / (float)lipL;
    float lt = rintf((float)d / cofv);

    sf[t] = lt; __syncthreads();
    for (int off = 256; off; off >>= 1) { if (t < off) sf[t] += sf[t + off]; __syncthreads(); }
    const float sumlt = sf[0]; __syncthreads();
    const float dif = (float)lipL - sumlt;

    sf[t] = lt; sx[t] = t; __syncthreads();
    for (int off = 256; off; off >>= 1) {
        if (t < off) {
            float v2 = sf[t + off]; int i2 = sx[t + off];
            if (v2 > sf[t] || (v2 == sf[t] && i2 < sx[t])) { sf[t] = v2; sx[t] = i2; }
        }
        __syncthreads();
    }
    const int max_idx = sx[0]; __syncthreads();
    if (t == max_idx) lt += dif;
    const int li = (int)lt;

    si[t] = li; __syncthreads();
    for (int off = 1; off < 512; off <<= 1) {
        int add = (t >= off) ? si[t - off] : 0;
        __syncthreads();
        si[t] += add;
        __syncthreads();
    }
    const int e = si[t];
    begins[b * TS + t] = e - li;
    ends[b * TS + t]   = e;
    if (t == 0) cof_arr[b] = cofv;
}

// ============================================================
// Kernel 3: batched fp32 GEMM. 128x128 tile, BK=16, 256 threads,
// 8x8 micro-tile. Double-buffered LDS, ONE barrier per kt,
// global->reg prefetch distance 2, staging overlapped with compute.
// ============================================================
#define G_STAGE(B, S)                                                          \
  { _Pragma("unroll")                                                          \
    for (int kk = 0; kk < 4; ++kk) {                                           \
      As[B][sub * 8 + kk][r]     = (&a0[S].x)[kk] * sA;                        \
      As[B][sub * 8 + 4 + kk][r] = (&a1[S].x)[kk] * sA;                        \
      Bs[B][sub * 8 + kk][r]     = (&b0[S].x)[kk] * sB;                        \
      Bs[B][sub * 8 + 4 + kk][r] = (&b1[S].x)[kk] * sB;                        \
    } }

#define G_COMPUTE(B)                                                           \
  { _Pragma("unroll")                                                          \
    for (int kk = 0; kk < 16; ++kk) {                                          \
      float4 t0 = *(const float4*)&As[B][kk][ty * 4];                          \
      float4 t1 = *(const float4*)&As[B][kk][64 + ty * 4];                     \
      float4 t2 = *(const float4*)&Bs[B][kk][tx * 4];                          \
      float4 t3 = *(const float4*)&Bs[B][kk][64 + tx * 4];                     \
      float a[8] = {t0.x, t0.y, t0.z, t0.w, t1.x, t1.y, t1.z, t1.w};           \
      float bbv[8] = {t2.x, t2.y, t2.z, t2.w, t3.x, t3.y, t3.z, t3.w};         \
      _Pragma("unroll")                                                        \
      for (int i = 0; i < 8; ++i)                                              \
        _Pragma("unroll")                                                      \
        for (int j = 0; j < 8; ++j)                                            \
          acc[i][j] = fmaf(a[i], bbv[j], acc[i][j]);                           \
    } }

#define G_ITER(KT, CB, NB)                                                     \
  {                                                                            \
    __syncthreads();                                                           \
    if ((KT) < 14) {                                                           \
      a0[CB] = *(const float4*)(Ag + ((KT) + 2) * 16);                         \
      a1[CB] = *(const float4*)(Ag + ((KT) + 2) * 16 + 4);                     \
      b0[CB] = *(const float4*)(Bg + ((KT) + 2) * 16);                         \
      b1[CB] = *(const float4*)(Bg + ((KT) + 2) * 16 + 4);                     \
    }                                                                          \
    if ((KT) < 15) G_STAGE(NB, NB);                                            \
    G_COMPUTE(CB);                                                             \
  }

__global__ __launch_bounds__(256) void gemm_kernel(const float* __restrict__ lip,
                                                   const float* __restrict__ phon,
                                                   const float* __restrict__ lip_scale,
                                                   const float* __restrict__ text_scale,
                                                   const int* __restrict__ begins,
                                                   const int* __restrict__ ends,
                                                   float* __restrict__ sim,
                                                   float* __restrict__ gt,
                                                   float* __restrict__ simT) {
    const int b = blockIdx.z, tm = blockIdx.y, tn = blockIdx.x;
    const int t = threadIdx.x;
    __shared__ __align__(16) float As[2][16][132];
    __shared__ __align__(16) float Bs[2][16][132];

    const int r = t >> 1, sub = t & 1;
    const int tx = t & 15, ty = t >> 4;

    const float* Ag = phon + ((size_t)(b * TS + tm * 128 + r)) * DD + sub * 8;
    const float* Bg = lip  + ((size_t)(b * TL + tn * 128 + r)) * DD + sub * 8;
    const float sA = text_scale[b * TS + tm * 128 + r];
    const float sB = lip_scale[b * TL + tn * 128 + r];

    float4 a0[2], a1[2], b0[2], b1[2];
    a0[0] = *(const float4*)(Ag);
    a1[0] = *(const float4*)(Ag + 4);
    b0[0] = *(const float4*)(Bg);
    b1[0] = *(const float4*)(Bg + 4);
    G_STAGE(0, 0);
    a0[1] = *(const float4*)(Ag + 16);
    a1[1] = *(const float4*)(Ag + 16 + 4);
    b0[1] = *(const float4*)(Bg + 16);
    b1[1] = *(const float4*)(Bg + 16 + 4);

    float acc[8][8];
    #pragma unroll
    for (int i = 0; i < 8; ++i)
        #pragma unroll
        for (int j = 0; j < 8; ++j) acc[i][j] = 0.0f;

    for (int kt = 0; kt < 16; kt += 2) {
        G_ITER(kt,     0, 1);
        G_ITER(kt + 1, 1, 0);
    }

    // epilogue: similarity + gt_similarity (x-major)
    const size_t base = (size_t)b * TS * TL;
    #pragma unroll
    for (int mi = 0; mi < 2; ++mi) {
        #pragma unroll
        for (int im = 0; im < 4; ++im) {
            const int srow = tm * 128 + mi * 64 + ty * 4 + im;
            const int ai = mi * 4 + im;
            float* prow = sim + base + (size_t)srow * TL + tn * 128;
            float4 w0 = {acc[ai][0], acc[ai][1], acc[ai][2], acc[ai][3]};
            float4 w1 = {acc[ai][4], acc[ai][5], acc[ai][6], acc[ai][7]};
            *(float4*)(prow + tx * 4) = w0;
            *(float4*)(prow + 64 + tx * 4) = w1;

            const int bg = begins[b * TS + srow], en = ends[b * TS + srow];
            const int l0 = tn * 128 + tx * 4;
            float4 g0, g1;
            g0.x = (l0 + 0 >= bg && l0 + 0 < en) ? 1.f : 0.f;
            g0.y = (l0 + 1 >= bg && l0 + 1 < en) ? 1.f : 0.f;
            g0.z = (l0 + 2 >= bg && l0 + 2 < en) ? 1.f : 0.f;
            g0.w = (l0 + 3 >= bg && l0 + 3 < en) ? 1.f : 0.f;
            g1.x = (l0 + 64 >= bg && l0 + 64 < en) ? 1.f : 0.f;
            g1.y = (l0 + 65 >= bg && l0 + 65 < en) ? 1.f : 0.f;
            g1.z = (l0 + 66 >= bg && l0 + 66 < en) ? 1.f : 0.f;
            g1.w = (l0 + 67 >= bg && l0 + 67 < en) ? 1.f : 0.f;
            float* grow = gt + base + (size_t)srow * TL + tn * 128;
            *(float4*)(grow + tx * 4) = g0;
            *(float4*)(grow + 64 + tx * 4) = g1;
        }
    }

    // transposed copy simT[b][l][s]  (row stride TS floats)
    {
        float* tb = simT + (size_t)b * TL * TS + (size_t)(tn * 128) * TS + tm * 128;
        #pragma unroll
        for (int bj = 0; bj < 8; ++bj) {
            const int lloc = (bj < 4) ? (tx * 4 + bj) : (64 + tx * 4 + (bj - 4));
            float* trow = tb + (size_t)lloc * TS;
            float4 w0 = {acc[0][bj], acc[1][bj], acc[2][bj], acc[3][bj]};
            float4 w1 = {acc[4][bj], acc[5][bj], acc[6][bj], acc[7][bj]};
            *(float4*)(trow + ty * 4) = w0;
            *(float4*)(trow + 64 + ty * 4) = w1;
        }
    }
}

// ============================================================
// Kernel 4: maximum_path DP — SYSTOLIC across 4 waves (256 thr).
// Wave k owns x in [128k, 128k+128); lane owns x0=128k+2*lane and
// x0+1. Wave k processes j-chunk c (32 steps) at superstep t=c+k;
// barrier-pipelined. Boundary value v[x0-1][j-1] crosses waves via
// a 96-deep rolling LDS ring per wave (slot = j mod 96): producer
// (lane 63) writes aligned float4 at chunk end; consumer reads
// aligned float4 blocks at chunk start. Liveness: consumer of
// chunk c reads slot-groups (c-1, c) mod 3; same-superstep
// producer writes group (c+1) mod 3 — disjoint. Ring zero-init
// supplies v_init=0 for j=-1. fmaf(val, xm, vmax) with xm in
// {0,1} is bit-identical to the reference's masked add.
// Stay bits packed MSB-first per 32-j word into dirs_lds (128 KB).
// ============================================================
#define DP_WAVES 4

template <bool CHK>
__device__ __forceinline__ void dp32(const float (&c0)[32], const float (&c1)[32],
                                     int j0, int x0, int lane,
                                     float xm0, float xm1,
                                     float& v0, float& v1,
                                     unsigned& w0, unsigned& w1,
                                     const float (&bw)[32], float (&bbf)[32]) {
    #pragma unroll
    for (int s = 0; s < 32; ++s) {
        const int j = j0 + s;
        float up = __shfl_up(v1, 1);
        up = (lane == 0) ? bw[s] : up;
        const float ov0 = v0;
        const unsigned st0 = (v0 >= up)  ? 1u : 0u;
        const unsigned st1 = (v1 >= ov0) ? 1u : 0u;
        float nv0 = fmaf(c0[s], xm0, fmaxf(v0, up));
        float nv1 = fmaf(c1[s], xm1, fmaxf(v1, ov0));
        if (CHK) {
            nv0 = (x0     <= j) ? nv0 : NEGV;
            nv1 = (x0 + 1 <= j) ? nv1 : NEGV;
        }
        w0 = w0 * 2u + st0;
        w1 = w1 * 2u + st1;
        bbf[s] = nv1;
        v0 = nv0; v1 = nv1;
    }
}

__device__ __forceinline__ void dp_superstep(const float* __restrict__ simTb,
                                             unsigned* __restrict__ dirs_lds,
                                             float* __restrict__ bndl,
                                             float (&cur0)[32], float (&cur1)[32],
                                             float (&nxt0)[32], float (&nxt1)[32],
                                             int T, int k, int lane, int x0, int nchunks,
                                             float xm0, float xm1,
                                             float& v0, float& v1,
                                             unsigned& w0, unsigned& w1) {
    __syncthreads();
    const int c  = T - k;
    const int cp = c + 1;
    if (cp >= 0 && cp < nchunks) {          // prefetch next chunk into nxt
        const int j0p = cp << 5;
        #pragma unroll
        for (int s = 0; s < 32; ++s) {
            float2 q = *(const float2*)(simTb + (size_t)(j0p + s) * TS + x0);
            nxt0[s] = q.x; nxt1[s] = q.y;
        }
    }
    if (c >= 0 && c < nchunks) {
        const int j0 = c << 5;
        float bw[32];
        if (k > 0) {                        // boundary window (lane-uniform broadcast reads)
            const float* br = bndl + (k - 1) * 96;
            const int r0 = j0 % 96;
            { float4 bq = *(const float4*)(br + ((r0 + 92) % 96)); bw[0] = bq.w; }
            #pragma unroll
            for (int q = 0; q < 8; ++q) {
                float4 bq = *(const float4*)(br + r0 + (q << 2));
                bw[4 * q + 1] = bq.x;
                bw[4 * q + 2] = bq.y;
                bw[4 * q + 3] = bq.z;
                if (4 * q + 4 < 32) bw[4 * q + 4] = bq.w;
            }
        } else {
            #pragma unroll
            for (int s = 0; s < 32; ++s) bw[s] = NEGV;
        }
        float bbf[32];
        if (c < 16) dp32<true >(cur0, cur1, j0, x0, lane, xm0, xm1, v0, v1, w0, w1, bw, bbf);
        else        dp32<false>(cur0, cur1, j0, x0, lane, xm0, xm1, v0, v1, w0, w1, bw, bbf);
        if (lane == 63) {                   // publish boundary values for wave k+1
            float* brw = bndl + k * 96 + (j0 % 96);
            #pragma unroll
            for (int q = 0; q < 8; ++q) {
                float4 w4 = {bbf[4*q], bbf[4*q+1], bbf[4*q+2], bbf[4*q+3]};
                *(float4*)(brw + 4 * q) = w4;
            }
        }
        dirs_lds[c * 512 + x0]     = w0;
        dirs_lds[c * 512 + x0 + 1] = w1;
        w0 = 0u; w1 = 0u;
    }
}

__global__ __launch_bounds__(256, 1) void dp_kernel(const float* __restrict__ simT,
                                                    const int* __restrict__ src_lens,
                                                    const int* __restrict__ lip_lens,
                                                    const float* __restrict__ cof_arr,
                                                    float* __restrict__ mean_out,
                                                    int* __restrict__ start2,
                                                    int* __restrict__ end2) {
    __shared__ unsigned dirs_lds[64 * 512];              // 128 KB
    __shared__ __align__(16) float bndl[DP_WAVES * 96];  // 1.5 KB boundary rings

    const int b = blockIdx.x, tid = threadIdx.x;
    const int k = tid >> 6, lane = tid & 63;
    const int x0 = (k << 7) + (lane << 1);

    if (b == 0 && tid == 0) {
        float s = 0.f;
        for (int i = 0; i < BATCH; ++i) s += cof_arr[i];
        mean_out[0] = s / 32.0f;
    }
    for (int i = tid; i < DP_WAVES * 96; i += 256) bndl[i] = 0.f;

    const int srcL = src_lens[b], lipL = lip_lens[b];
    const float* simTb = simT + (size_t)b * TL * TS;
    const int nchunks = (lipL + 31) >> 5;            // 32..64

    const float xm0 = (x0     < srcL) ? 1.f : 0.f;
    const float xm1 = (x0 + 1 < srcL) ? 1.f : 0.f;
    float v0 = 0.f, v1 = 0.f;
    unsigned w0 = 0u, w1 = 0u;

    float curA0[32], curA1[32], curB0[32], curB1[32];
    if (k == 0) {                                    // wave 0 preloads chunk 0 -> buf A
        #pragma unroll
        for (int s = 0; s < 32; ++s) {
            float2 q = *(const float2*)(simTb + (size_t)s * TS + x0);
            curA0[s] = q.x; curA1[s] = q.y;
        }
    }

    const int tot = nchunks + DP_WAVES - 1;
    for (int t = 0; t < tot; t += 2) {
        dp_superstep(simTb, dirs_lds, bndl, curA0, curA1, curB0, curB1,
                     t, k, lane, x0, nchunks, xm0, xm1, v0, v1, w0, w1);
        if (t + 1 < tot)
            dp_superstep(simTb, dirs_lds, bndl, curB0, curB1, curA0, curA1,
                         t + 1, k, lane, x0, nchunks, xm0, xm1, v0, v1, w0, w1);
    }

    // ---- zero outputs, then backtrack on wave 0 ----
    start2[b * TS + tid]       = 0;
    end2[b * TS + tid]         = 0;
    start2[b * TS + tid + 256] = 0;
    end2[b * TS + tid + 256]   = 0;
    asm volatile("s_waitcnt vmcnt(0)" ::: "memory");
    __syncthreads();   // zeros from ALL waves drained before wave 0's stores

    if (k == 0) {
        int x = srcL - 1;
        if (lane == 0) end2[b * TS + x] = lipL;
        int j = lipL - 1;
        while (x > 0 && j >= 0) {
            const unsigned W = dirs_lds[(j >> 5) * 512 + x];
            const int jj = j & 31;
            const unsigned m = (~W) & (0xFFFFFFFFu << (31 - jj));
            if (m == 0u) { j -= jj + 1; continue; }
            const int jp = __builtin_ctz(m);
            const int jprime = (j & ~31) + (31 - jp);
            if (lane == 0) { start2[b * TS + x] = jprime; end2[b * TS + x - 1] = jprime; }
            x -= 1; j = jprime - 1;
        }
    }
}

// ============================================================
// Kernel 5: alignment rows (run indicators) + d_predictions
// ============================================================
__global__ __launch_bounds__(256) void align_kernel(const int* __restrict__ start2,
                                                    const int* __restrict__ end2,
                                                    const float* __restrict__ mean_cof,
                                                    float* __restrict__ alignOut,
                                                    float* __restrict__ dpred) {
    const int s = blockIdx.x, b = blockIdx.y, t = threadIdx.x;
    const int st = start2[b * TS + s], en = end2[b * TS + s];
    float* row = alignOut + ((size_t)b * TS + s) * TL;
    const int l0 = t * 8;
    float4 r0, r1;
    r0.x = (l0 + 0 >= st && l0 + 0 < en) ? 1.f : 0.f;
    r0.y = (l0 + 1 >= st && l0 + 1 < en) ? 1.f : 0.f;
    r0.z = (l0 + 2 >= st && l0 + 2 < en) ? 1.f : 0.f;
    r0.w = (l0 + 3 >= st && l0 + 3 < en) ? 1.f : 0.f;
    r1.x = (l0 + 4 >= st && l0 + 4 < en) ? 1.f : 0.f;
    r1.y = (l0 + 5 >= st && l0 + 5 < en) ? 1.f : 0.f;
    r1.z = (l0 + 6 >= st && l0 + 6 < en) ? 1.f : 0.f;
    r1.w = (l0 + 7 >= st && l0 + 7 < en) ? 1.f : 0.f;
    *(float4*)(row + l0) = r0;
    *(float4*)(row + l0 + 4) = r1;
    if (t == 0) dpred[b * TS + s] = (float)(en - st) * mean_cof[0];
}

// ============================================================
extern "C" void kernel_launch(void* const* d_in, const int* in_sizes, int n_in,
                              void* d_out, int out_size, void* d_ws, size_t ws_size,
                              hipStream_t stream) {
    const float* lip   = (const float*)d_in[0];
    const float* phon  = (const float*)d_in[1];
    const int* d_tg    = (const int*)d_in[2];
    const int* src_l   = (const int*)d_in[3];
    const int* lip_l   = (const int*)d_in[4];
    float* out = (float*)d_out;

    char* ws = (char*)d_ws;
    float*    mean_cof   = (float*)(ws + WS_MEAN);
    float*    cof_arr    = (float*)(ws + WS_COF);
    float*    lip_scale  = (float*)(ws + WS_LSCALE);
    float*    text_scale = (float*)(ws + WS_TSCALE);
    int*      begins     = (int*)(ws + WS_BEGIN);
    int*      ends       = (int*)(ws + WS_END);
    int*      start2     = (int*)(ws + WS_START2);
    int*      end2       = (int*)(ws + WS_END2);

    float* sim   = out + SIM_OFF;
    float* gt    = out + GT_OFF;
    float* aln   = out + ALIGN_OFF;   // doubles as simT scratch before align_kernel
    float* dpred = out + DPRED_OFF;

    norm_kernel<<<(BATCH * TL + BATCH * TS) / 4, 256, 0, stream>>>(lip, phon, lip_scale, text_scale);
    prep_kernel<<<BATCH, 512, 0, stream>>>(d_tg, lip_l, begins, ends, cof_arr);
    gemm_kernel<<<dim3(TL / 128, TS / 128, BATCH), 256, 0, stream>>>(lip, phon, lip_scale, text_scale,
                                                                     begins, ends, sim, gt, aln);
    dp_kernel<<<BATCH, 256, 0, stream>>>(aln, src_l, lip_l, cof_arr, mean_cof, start2, end2);
    align_kernel<<<dim3(TS, BATCH), 256, 0, stream>>>(start2, end2, mean_cof, aln, dpred);
}

// Round 5
// 985.340 us; speedup vs baseline: 1.0579x; 1.0579x over previous
//
#include <hip/hip_runtime.h>
#include <math.h>

// Problem constants (fixed by setup_inputs)
#define BATCH 32
#define TS    512     // Ts (phonemes / Tx)
#define TL    2048    // Tl (lip frames / Ty)
#define DD    256     // embedding dim
#define NEGV  -1e9f

// d_out sections (floats)
#define SIM_OFF   ((size_t)0)
#define GT_OFF    ((size_t)BATCH*TS*TL)
#define ALIGN_OFF ((size_t)2*BATCH*TS*TL)
#define DPRED_OFF ((size_t)3*BATCH*TS*TL)

// ---------------- ws layout (bytes) ----------------
#define WS_MEAN   0
#define WS_COF    256
#define WS_LSCALE 512
#define WS_TSCALE 262656
#define WS_BEGIN  328192
#define WS_END    393728
#define WS_START2 459264
#define WS_END2   524800

// ============================================================
// Kernel 1: row norms -> scales.
// ============================================================
__global__ __launch_bounds__(256) void norm_kernel(const float* __restrict__ lip,
                                                   const float* __restrict__ phon,
                                                   float* __restrict__ lip_scale,
                                                   float* __restrict__ text_scale) {
    const int wave = threadIdx.x >> 6, lane = threadIdx.x & 63;
    const int row = blockIdx.x * 4 + wave;
    const int NL = BATCH * TL;
    const float* src = (row < NL) ? (lip + (size_t)row * DD)
                                  : (phon + (size_t)(row - NL) * DD);
    float4 q = *(const float4*)(src + lane * 4);
    float ss = q.x*q.x + q.y*q.y + q.z*q.z + q.w*q.w;
    #pragma unroll
    for (int off = 32; off; off >>= 1) ss += __shfl_xor(ss, off);
    if (lane == 0) {
        if (row < NL) lip_scale[row] = 1.0f / sqrtf(ss);
        else          text_scale[row - NL] = 1.0f / (sqrtf(ss) + 1.0f);
    }
}

// ============================================================
// Kernel 2: per-batch duration prep. One block (512 thr) per batch.
// ============================================================
__global__ __launch_bounds__(512) void prep_kernel(const int* __restrict__ d_targets,
                                                   const int* __restrict__ lip_lens,
                                                   int* __restrict__ begins,
                                                   int* __restrict__ ends,
                                                   float* __restrict__ cof_arr) {
    __shared__ int   si[512];
    __shared__ float sf[512];
    __shared__ int   sx[512];
    const int b = blockIdx.x, t = threadIdx.x;
    const int d = d_targets[b * TS + t];
    const int lipL = lip_lens[b];

    si[t] = d; __syncthreads();
    for (int off = 256; off; off >>= 1) { if (t < off) si[t] += si[t + off]; __syncthreads(); }
    const int sum_d = si[0]; __syncthreads();

    const float cofv = (float)sum_d / (float)lipL;
    float lt = rintf((float)d / cofv);

    sf[t] = lt; __syncthreads();
    for (int off = 256; off; off >>= 1) { if (t < off) sf[t] += sf[t + off]; __syncthreads(); }
    const float sumlt = sf[0]; __syncthreads();
    const float dif = (float)lipL - sumlt;

    sf[t] = lt; sx[t] = t; __syncthreads();
    for (int off = 256; off; off >>= 1) {
        if (t < off) {
            float v2 = sf[t + off]; int i2 = sx[t + off];
            if (v2 > sf[t] || (v2 == sf[t] && i2 < sx[t])) { sf[t] = v2; sx[t] = i2; }
        }
        __syncthreads();
    }
    const int max_idx = sx[0]; __syncthreads();
    if (t == max_idx) lt += dif;
    const int li = (int)lt;

    si[t] = li; __syncthreads();
    for (int off = 1; off < 512; off <<= 1) {
        int add = (t >= off) ? si[t - off] : 0;
        __syncthreads();
        si[t] += add;
        __syncthreads();
    }
    const int e = si[t];
    begins[b * TS + t] = e - li;
    ends[b * TS + t]   = e;
    if (t == 0) cof_arr[b] = cofv;
}

// ============================================================
// Kernel 3: batched fp32 GEMM — REVERTED to the R2 single-buffered
// version (the LDS double-buffer regressed: VGPR 168->200 cut
// occupancy, 361 vs ~330 us). 128x128 tile, BK=16, 256 threads,
// 8x8 micro-tile, scales applied on stage-in, gt fused, simT
// transposed copy for the DP kernel.
// ============================================================
__global__ __launch_bounds__(256) void gemm_kernel(const float* __restrict__ lip,
                                                   const float* __restrict__ phon,
                                                   const float* __restrict__ lip_scale,
                                                   const float* __restrict__ text_scale,
                                                   const int* __restrict__ begins,
                                                   const int* __restrict__ ends,
                                                   float* __restrict__ sim,
                                                   float* __restrict__ gt,
                                                   float* __restrict__ simT) {
    const int b = blockIdx.z, tm = blockIdx.y, tn = blockIdx.x;
    const int t = threadIdx.x;
    __shared__ __align__(16) float As[16][132];
    __shared__ __align__(16) float Bs[16][132];

    const int r = t >> 1, sub = t & 1;
    const int tx = t & 15, ty = t >> 4;

    const float* Ag = phon + ((size_t)(b * TS + tm * 128 + r)) * DD + sub * 8;
    const float* Bg = lip  + ((size_t)(b * TL + tn * 128 + r)) * DD + sub * 8;
    const float sA = text_scale[b * TS + tm * 128 + r];
    const float sB = lip_scale[b * TL + tn * 128 + r];

    float4 ra0 = *(const float4*)(Ag);
    float4 ra1 = *(const float4*)(Ag + 4);
    float4 rb0 = *(const float4*)(Bg);
    float4 rb1 = *(const float4*)(Bg + 4);

    float acc[8][8];
    #pragma unroll
    for (int i = 0; i < 8; ++i)
        #pragma unroll
        for (int j = 0; j < 8; ++j) acc[i][j] = 0.0f;

    for (int kt = 0; kt < 16; ++kt) {
        __syncthreads();
        {
            const float* pa0 = &ra0.x; const float* pa1 = &ra1.x;
            const float* pb0 = &rb0.x; const float* pb1 = &rb1.x;
            #pragma unroll
            for (int kk = 0; kk < 4; ++kk) {
                As[sub * 8 + kk][r]     = pa0[kk] * sA;
                As[sub * 8 + 4 + kk][r] = pa1[kk] * sA;
                Bs[sub * 8 + kk][r]     = pb0[kk] * sB;
                Bs[sub * 8 + 4 + kk][r] = pb1[kk] * sB;
            }
        }
        __syncthreads();
        if (kt < 15) {
            ra0 = *(const float4*)(Ag + (kt + 1) * 16);
            ra1 = *(const float4*)(Ag + (kt + 1) * 16 + 4);
            rb0 = *(const float4*)(Bg + (kt + 1) * 16);
            rb1 = *(const float4*)(Bg + (kt + 1) * 16 + 4);
        }
        #pragma unroll
        for (int kk = 0; kk < 16; ++kk) {
            float4 t0 = *(const float4*)&As[kk][ty * 4];
            float4 t1 = *(const float4*)&As[kk][64 + ty * 4];
            float4 t2 = *(const float4*)&Bs[kk][tx * 4];
            float4 t3 = *(const float4*)&Bs[kk][64 + tx * 4];
            float a[8] = {t0.x, t0.y, t0.z, t0.w, t1.x, t1.y, t1.z, t1.w};
            float bb[8] = {t2.x, t2.y, t2.z, t2.w, t3.x, t3.y, t3.z, t3.w};
            #pragma unroll
            for (int i = 0; i < 8; ++i)
                #pragma unroll
                for (int j = 0; j < 8; ++j)
                    acc[i][j] = fmaf(a[i], bb[j], acc[i][j]);
        }
    }

    // epilogue: similarity + gt_similarity (x-major)
    const size_t base = (size_t)b * TS * TL;
    #pragma unroll
    for (int mi = 0; mi < 2; ++mi) {
        #pragma unroll
        for (int im = 0; im < 4; ++im) {
            const int srow = tm * 128 + mi * 64 + ty * 4 + im;
            const int ai = mi * 4 + im;
            float* prow = sim + base + (size_t)srow * TL + tn * 128;
            float4 w0 = {acc[ai][0], acc[ai][1], acc[ai][2], acc[ai][3]};
            float4 w1 = {acc[ai][4], acc[ai][5], acc[ai][6], acc[ai][7]};
            *(float4*)(prow + tx * 4) = w0;
            *(float4*)(prow + 64 + tx * 4) = w1;

            const int bg = begins[b * TS + srow], en = ends[b * TS + srow];
            const int l0 = tn * 128 + tx * 4;
            float4 g0, g1;
            g0.x = (l0 + 0 >= bg && l0 + 0 < en) ? 1.f : 0.f;
            g0.y = (l0 + 1 >= bg && l0 + 1 < en) ? 1.f : 0.f;
            g0.z = (l0 + 2 >= bg && l0 + 2 < en) ? 1.f : 0.f;
            g0.w = (l0 + 3 >= bg && l0 + 3 < en) ? 1.f : 0.f;
            g1.x = (l0 + 64 >= bg && l0 + 64 < en) ? 1.f : 0.f;
            g1.y = (l0 + 65 >= bg && l0 + 65 < en) ? 1.f : 0.f;
            g1.z = (l0 + 66 >= bg && l0 + 66 < en) ? 1.f : 0.f;
            g1.w = (l0 + 67 >= bg && l0 + 67 < en) ? 1.f : 0.f;
            float* grow = gt + base + (size_t)srow * TL + tn * 128;
            *(float4*)(grow + tx * 4) = g0;
            *(float4*)(grow + 64 + tx * 4) = g1;
        }
    }

    // transposed copy simT[b][l][s]  (row stride TS floats)
    {
        float* tb = simT + (size_t)b * TL * TS + (size_t)(tn * 128) * TS + tm * 128;
        #pragma unroll
        for (int bj = 0; bj < 8; ++bj) {
            const int lloc = (bj < 4) ? (tx * 4 + bj) : (64 + tx * 4 + (bj - 4));
            float* trow = tb + (size_t)lloc * TS;
            float4 w0 = {acc[0][bj], acc[1][bj], acc[2][bj], acc[3][bj]};
            float4 w1 = {acc[4][bj], acc[5][bj], acc[6][bj], acc[7][bj]};
            *(float4*)(trow + ty * 4) = w0;
            *(float4*)(trow + 64 + ty * 4) = w1;
        }
    }
}

// ============================================================
// Kernel 4: maximum_path DP — 4-wave systolic, NOW with prefetch
// distance 2 supersteps (3 register buffer pairs). Loads for chunk
// c+2 issue at superstep t=c+k; consumed at t+2 (~2 barriers,
// ~2400 cyc in flight > HBM latency) so the per-superstep vmcnt
// stall of the 1-deep version disappears. Buffer rotation by
// wave-local phase (T-k) mod 3 via wave-uniform switch with STATIC
// buffer names (no dynamic indexing -> no scratch). Barrier outside
// the switch: all waves sync together.
// Ring liveness: producer writes group c%3 at t=c+k; consumer (wave
// k+1) reads it at t+1; group rewritten at t+3. Safe.
// ============================================================
#define DP_WAVES 4

template <bool CHK>
__device__ __forceinline__ void dp32(const float (&c0)[32], const float (&c1)[32],
                                     int j0, int x0, int lane,
                                     float xm0, float xm1,
                                     float& v0, float& v1,
                                     unsigned& w0, unsigned& w1,
                                     const float (&bw)[32], float (&bbf)[32]) {
    #pragma unroll
    for (int s = 0; s < 32; ++s) {
        const int j = j0 + s;
        float up = __shfl_up(v1, 1);
        up = (lane == 0) ? bw[s] : up;
        const float ov0 = v0;
        const unsigned st0 = (v0 >= up)  ? 1u : 0u;
        const unsigned st1 = (v1 >= ov0) ? 1u : 0u;
        float nv0 = fmaf(c0[s], xm0, fmaxf(v0, up));
        float nv1 = fmaf(c1[s], xm1, fmaxf(v1, ov0));
        if (CHK) {
            nv0 = (x0     <= j) ? nv0 : NEGV;
            nv1 = (x0 + 1 <= j) ? nv1 : NEGV;
        }
        w0 = w0 * 2u + st0;
        w1 = w1 * 2u + st1;
        bbf[s] = nv1;
        v0 = nv0; v1 = nv1;
    }
}

__device__ __forceinline__ void dp_chunk_load(const float* __restrict__ simTb,
                                              float (&d0)[32], float (&d1)[32],
                                              int c, int x0) {
    const int j0p = c << 5;
    #pragma unroll
    for (int s = 0; s < 32; ++s) {
        float2 q = *(const float2*)(simTb + (size_t)(j0p + s) * TS + x0);
        d0[s] = q.x; d1[s] = q.y;
    }
}

__device__ __forceinline__ void dp_superstep(const float* __restrict__ simTb,
                                             unsigned* __restrict__ dirs_lds,
                                             float* __restrict__ bndl,
                                             float (&cur0)[32], float (&cur1)[32],
                                             float (&tgt0)[32], float (&tgt1)[32],
                                             int T, int k, int lane, int x0, int nchunks,
                                             float xm0, float xm1,
                                             float& v0, float& v1,
                                             unsigned& w0, unsigned& w1) {
    const int c   = T - k;
    const int cp2 = c + 2;
    if (cp2 >= 0 && cp2 < nchunks)          // prefetch chunk c+2 (distance 2)
        dp_chunk_load(simTb, tgt0, tgt1, cp2, x0);
    if (c >= 0 && c < nchunks) {
        const int j0 = c << 5;
        float bw[32];
        if (k > 0) {                        // boundary window (lane-uniform broadcast reads)
            const float* br = bndl + (k - 1) * 96;
            const int r0 = j0 % 96;
            { float4 bq = *(const float4*)(br + ((r0 + 92) % 96)); bw[0] = bq.w; }
            #pragma unroll
            for (int q = 0; q < 8; ++q) {
                float4 bq = *(const float4*)(br + r0 + (q << 2));
                bw[4 * q + 1] = bq.x;
                bw[4 * q + 2] = bq.y;
                bw[4 * q + 3] = bq.z;
                if (4 * q + 4 < 32) bw[4 * q + 4] = bq.w;
            }
        } else {
            #pragma unroll
            for (int s = 0; s < 32; ++s) bw[s] = NEGV;
        }
        float bbf[32];
        if (c < 16) dp32<true >(cur0, cur1, j0, x0, lane, xm0, xm1, v0, v1, w0, w1, bw, bbf);
        else        dp32<false>(cur0, cur1, j0, x0, lane, xm0, xm1, v0, v1, w0, w1, bw, bbf);
        if (lane == 63) {                   // publish boundary values for wave k+1
            float* brw = bndl + k * 96 + (j0 % 96);
            #pragma unroll
            for (int q = 0; q < 8; ++q) {
                float4 w4 = {bbf[4*q], bbf[4*q+1], bbf[4*q+2], bbf[4*q+3]};
                *(float4*)(brw + 4 * q) = w4;
            }
        }
        dirs_lds[c * 512 + x0]     = w0;
        dirs_lds[c * 512 + x0 + 1] = w1;
        w0 = 0u; w1 = 0u;
    }
}

__global__ __launch_bounds__(256, 1) void dp_kernel(const float* __restrict__ simT,
                                                    const int* __restrict__ src_lens,
                                                    const int* __restrict__ lip_lens,
                                                    const float* __restrict__ cof_arr,
                                                    float* __restrict__ mean_out,
                                                    int* __restrict__ start2,
                                                    int* __restrict__ end2) {
    __shared__ unsigned dirs_lds[64 * 512];              // 128 KB
    __shared__ __align__(16) float bndl[DP_WAVES * 96];  // 1.5 KB boundary rings

    const int b = blockIdx.x, tid = threadIdx.x;
    const int k = tid >> 6, lane = tid & 63;
    const int x0 = (k << 7) + (lane << 1);

    if (b == 0 && tid == 0) {
        float s = 0.f;
        for (int i = 0; i < BATCH; ++i) s += cof_arr[i];
        mean_out[0] = s / 32.0f;
    }
    for (int i = tid; i < DP_WAVES * 96; i += 256) bndl[i] = 0.f;

    const int srcL = src_lens[b], lipL = lip_lens[b];
    const float* simTb = simT + (size_t)b * TL * TS;
    const int nchunks = (lipL + 31) >> 5;            // 32..64

    const float xm0 = (x0     < srcL) ? 1.f : 0.f;
    const float xm1 = (x0 + 1 < srcL) ? 1.f : 0.f;
    float v0 = 0.f, v1 = 0.f;
    unsigned w0 = 0u, w1 = 0u;

    // 3 buffer pairs: chunk c lives in buf[c % 3]  (A=0, B=1, C=2)
    float cA0[32], cA1[32], cB0[32], cB1[32], cC0[32], cC1[32];

    // prologue preloads: wave k computes chunk c at T=c+k; in-loop issue
    // happens at T=c+k-2, so chunks with c+k<2 need preloading here.
    if (k == 0) {
        dp_chunk_load(simTb, cA0, cA1, 0, x0);       // chunk 0 -> A
        dp_chunk_load(simTb, cB0, cB1, 1, x0);       // chunk 1 -> B
    } else if (k == 1) {
        dp_chunk_load(simTb, cA0, cA1, 0, x0);       // chunk 0 -> A
    }

    const int tot = nchunks + DP_WAVES - 1;
    int phase = (3 - (k % 3)) % 3;                   // (T - k) mod 3 at T=0
    for (int T = 0; T < tot; ++T) {
        __syncthreads();
        if (phase == 0)                              // cur = A, prefetch -> C
            dp_superstep(simTb, dirs_lds, bndl, cA0, cA1, cC0, cC1,
                         T, k, lane, x0, nchunks, xm0, xm1, v0, v1, w0, w1);
        else if (phase == 1)                         // cur = B, prefetch -> A
            dp_superstep(simTb, dirs_lds, bndl, cB0, cB1, cA0, cA1,
                         T, k, lane, x0, nchunks, xm0, xm1, v0, v1, w0, w1);
        else                                         // cur = C, prefetch -> B
            dp_superstep(simTb, dirs_lds, bndl, cC0, cC1, cB0, cB1,
                         T, k, lane, x0, nchunks, xm0, xm1, v0, v1, w0, w1);
        phase = (phase + 1 == 3) ? 0 : phase + 1;
    }

    // ---- zero outputs, then backtrack on wave 0 ----
    start2[b * TS + tid]       = 0;
    end2[b * TS + tid]         = 0;
    start2[b * TS + tid + 256] = 0;
    end2[b * TS + tid + 256]   = 0;
    asm volatile("s_waitcnt vmcnt(0)" ::: "memory");
    __syncthreads();   // zeros from ALL waves drained before wave 0's stores

    if (k == 0) {
        int x = srcL - 1;
        if (lane == 0) end2[b * TS + x] = lipL;
        int j = lipL - 1;
        while (x > 0 && j >= 0) {
            const unsigned W = dirs_lds[(j >> 5) * 512 + x];
            const int jj = j & 31;
            const unsigned m = (~W) & (0xFFFFFFFFu << (31 - jj));
            if (m == 0u) { j -= jj + 1; continue; }
            const int jp = __builtin_ctz(m);
            const int jprime = (j & ~31) + (31 - jp);
            if (lane == 0) { start2[b * TS + x] = jprime; end2[b * TS + x - 1] = jprime; }
            x -= 1; j = jprime - 1;
        }
    }
}

// ============================================================
// Kernel 5: alignment rows (run indicators) + d_predictions
// ============================================================
__global__ __launch_bounds__(256) void align_kernel(const int* __restrict__ start2,
                                                    const int* __restrict__ end2,
                                                    const float* __restrict__ mean_cof,
                                                    float* __restrict__ alignOut,
                                                    float* __restrict__ dpred) {
    const int s = blockIdx.x, b = blockIdx.y, t = threadIdx.x;
    const int st = start2[b * TS + s], en = end2[b * TS + s];
    float* row = alignOut + ((size_t)b * TS + s) * TL;
    const int l0 = t * 8;
    float4 r0, r1;
    r0.x = (l0 + 0 >= st && l0 + 0 < en) ? 1.f : 0.f;
    r0.y = (l0 + 1 >= st && l0 + 1 < en) ? 1.f : 0.f;
    r0.z = (l0 + 2 >= st && l0 + 2 < en) ? 1.f : 0.f;
    r0.w = (l0 + 3 >= st && l0 + 3 < en) ? 1.f : 0.f;
    r1.x = (l0 + 4 >= st && l0 + 4 < en) ? 1.f : 0.f;
    r1.y = (l0 + 5 >= st && l0 + 5 < en) ? 1.f : 0.f;
    r1.z = (l0 + 6 >= st && l0 + 6 < en) ? 1.f : 0.f;
    r1.w = (l0 + 7 >= st && l0 + 7 < en) ? 1.f : 0.f;
    *(float4*)(row + l0) = r0;
    *(float4*)(row + l0 + 4) = r1;
    if (t == 0) dpred[b * TS + s] = (float)(en - st) * mean_cof[0];
}

// ============================================================
extern "C" void kernel_launch(void* const* d_in, const int* in_sizes, int n_in,
                              void* d_out, int out_size, void* d_ws, size_t ws_size,
                              hipStream_t stream) {
    const float* lip   = (const float*)d_in[0];
    const float* phon  = (const float*)d_in[1];
    const int* d_tg    = (const int*)d_in[2];
    const int* src_l   = (const int*)d_in[3];
    const int* lip_l   = (const int*)d_in[4];
    float* out = (float*)d_out;

    char* ws = (char*)d_ws;
    float*    mean_cof   = (float*)(ws + WS_MEAN);
    float*    cof_arr    = (float*)(ws + WS_COF);
    float*    lip_scale  = (float*)(ws + WS_LSCALE);
    float*    text_scale = (float*)(ws + WS_TSCALE);
    int*      begins     = (int*)(ws + WS_BEGIN);
    int*      ends       = (int*)(ws + WS_END);
    int*      start2     = (int*)(ws + WS_START2);
    int*      end2       = (int*)(ws + WS_END2);

    float* sim   = out + SIM_OFF;
    float* gt    = out + GT_OFF;
    float* aln   = out + ALIGN_OFF;   // doubles as simT scratch before align_kernel
    float* dpred = out + DPRED_OFF;

    norm_kernel<<<(BATCH * TL + BATCH * TS) / 4, 256, 0, stream>>>(lip, phon, lip_scale, text_scale);
    prep_kernel<<<BATCH, 512, 0, stream>>>(d_tg, lip_l, begins, ends, cof_arr);
    gemm_kernel<<<dim3(TL / 128, TS / 128, BATCH), 256, 0, stream>>>(lip, phon, lip_scale, text_scale,
                                                                     begins, ends, sim, gt, aln);
    dp_kernel<<<BATCH, 256, 0, stream>>>(aln, src_l, lip_l, cof_arr, mean_cof, start2, end2);
    align_kernel<<<dim3(TS, BATCH), 256, 0, stream>>>(start2, end2, mean_cof, aln, dpred);
}